// Round 3
// baseline (786.852 us; speedup 1.0000x reference)
//
#include <hip/hip_runtime.h>
#include <hip/hip_bf16.h>

#define NN 16384
#define DD 128
#define KSTEPS (NN / 32)   // 512 K-steps of 32

typedef __attribute__((ext_vector_type(8))) short short8;
typedef __attribute__((ext_vector_type(4))) float f32x4;

__device__ __forceinline__ short f2bf(float f) {
  union { float f; unsigned u; } v; v.f = f;
  unsigned r = v.u + 0x7fffu + ((v.u >> 16) & 1u);   // RNE f32->bf16
  return (short)(r >> 16);
}
__device__ __forceinline__ float bf2f(short s) {
  union { unsigned u; float f; } v; v.u = ((unsigned)(unsigned short)s) << 16;
  return v.f;
}

// ---------------------------------------------------------------------------
// small GEMM: T = In @ W, written in MFMA B-fragment-major layout:
//   element (d, k):  kt=k>>5, dt=d>>4, lane=(d&15)|(((k>>3)&3)<<4), e=k&7
//   Tf[(((kt*8)+dt)*64 + lane)*8 + e]
// ---------------------------------------------------------------------------
template<int IN_BF16>
__global__ __launch_bounds__(256, 1)
void small_gemm(const void* __restrict__ In_, const float* __restrict__ W,
                short* __restrict__ Tf)
{
  __shared__ float sW[DD * DD];   // 64 KB
  const int tid = threadIdx.x;
  {
    const float4* W4 = (const float4*)W;
    float4* sW4 = (float4*)sW;
#pragma unroll
    for (int i = 0; i < 16; ++i) sW4[tid + 256 * i] = W4[tid + 256 * i];
  }
  __syncthreads();

  const int k0 = blockIdx.x * 16;
  const int kk = tid & 15;        // k-row within tile
  const int q  = tid >> 4;        // d-chunk 0..15 -> d = 8q..8q+7
  const long rowoff = (long)(k0 + kk) * DD;

  float acc[8] = {0.f, 0.f, 0.f, 0.f, 0.f, 0.f, 0.f, 0.f};
  if (IN_BF16) {
    const short8* In8 = (const short8*)((const short*)In_ + rowoff);
    for (int j8 = 0; j8 < 16; ++j8) {
      short8 a8 = In8[j8];
#pragma unroll
      for (int c = 0; c < 8; ++c) {
        float a = bf2f(a8[c]);
#pragma unroll
        for (int dd = 0; dd < 8; ++dd)
          acc[dd] += a * sW[(j8 * 8 + c) * DD + q * 8 + dd];
      }
    }
  } else {
    const float4* In4 = (const float4*)((const float*)In_ + rowoff);
    for (int j4 = 0; j4 < 32; ++j4) {
      float4 a4 = In4[j4];
      float av[4] = {a4.x, a4.y, a4.z, a4.w};
#pragma unroll
      for (int c = 0; c < 4; ++c)
#pragma unroll
        for (int dd = 0; dd < 8; ++dd)
          acc[dd] += av[c] * sW[(j4 * 4 + c) * DD + q * 8 + dd];
    }
  }

  const int k    = k0 + kk;
  const int kt   = k >> 5;
  const int ksub = (k >> 3) & 3;
  const int e    = k & 7;
#pragma unroll
  for (int dd = 0; dd < 8; ++dd) {
    const int d  = q * 8 + dd;
    const int dt = d >> 4;
    const int lf = (d & 15) | (ksub << 4);
    Tf[((((long)kt * 8) + dt) * 64 + lf) * 8 + e] = f2bf(acc[dd]);
  }
}

// ---------------------------------------------------------------------------
// aggregation: Out = relu(A @ T), T fragment-major bf16.
// One wave per block; wave owns 16 rows x all 128 cols. NO LDS, NO barriers.
// A-fragment loaded directly from global (row = lane&15, k = (lane>>4)*8+e),
// converted fp32->bf16 in-register. 3-deep named register pipeline so
// outstanding HBM loads never drain to zero.
// ---------------------------------------------------------------------------
template<int WRITE_BF16>
__global__ __launch_bounds__(64, 1)
void agg_kernel(const float* __restrict__ A, const short* __restrict__ Bf,
                void* __restrict__ out_)
{
  const int lane = threadIdx.x;       // 0..63
  const long r0  = (long)blockIdx.x * 16;
  const int arow = lane & 15;
  const int kgrp = lane >> 4;         // 0..3

  const float* aptr = A + (r0 + arow) * (long)NN + kgrp * 8;
  const short* bptr = Bf + lane * 8;

  f32x4 acc[8];
#pragma unroll
  for (int dt = 0; dt < 8; ++dt) acc[dt] = (f32x4){0.f, 0.f, 0.f, 0.f};

  auto LOADA = [&](float4 (&xa)[2], int t) {
    const float* p = aptr + (long)t * 32;
    xa[0] = *(const float4*)p;
    xa[1] = *(const float4*)(p + 4);
  };
  auto LOADB = [&](short8 (&xb)[8], int t) {
    const short* p = bptr + (long)t * 4096;
#pragma unroll
    for (int dt = 0; dt < 8; ++dt)
      xb[dt] = *(const short8*)(p + dt * 512);
  };
  auto STEP = [&](float4 (&xa)[2], short8 (&xb)[8]) {
    short8 af;
    af[0] = f2bf(xa[0].x); af[1] = f2bf(xa[0].y);
    af[2] = f2bf(xa[0].z); af[3] = f2bf(xa[0].w);
    af[4] = f2bf(xa[1].x); af[5] = f2bf(xa[1].y);
    af[6] = f2bf(xa[1].z); af[7] = f2bf(xa[1].w);
#pragma unroll
    for (int dt = 0; dt < 8; ++dt)
      acc[dt] = __builtin_amdgcn_mfma_f32_16x16x32_bf16(af, xb[dt], acc[dt], 0, 0, 0);
  };

  float4 a0[2], a1[2], a2[2];
  short8 b0[8], b1[8], b2[8];
  LOADA(a0, 0); LOADB(b0, 0);
  LOADA(a1, 1); LOADB(b1, 1);
  LOADA(a2, 2); LOADB(b2, 2);

  for (int t = 0; t < KSTEPS; t += 3) {
    STEP(a0, b0);
    if (t + 3 < KSTEPS) { LOADA(a0, t + 3); LOADB(b0, t + 3); }
    if (t + 1 < KSTEPS) {
      STEP(a1, b1);
      if (t + 4 < KSTEPS) { LOADA(a1, t + 4); LOADB(b1, t + 4); }
    }
    if (t + 2 < KSTEPS) {
      STEP(a2, b2);
      if (t + 5 < KSTEPS) { LOADA(a2, t + 5); LOADB(b2, t + 5); }
    }
  }

  // epilogue: relu + store (C layout: row = kgrp*4 + r, col = lane&15)
#pragma unroll
  for (int dt = 0; dt < 8; ++dt) {
#pragma unroll
    for (int r = 0; r < 4; ++r) {
      float v = acc[dt][r];
      v = v > 0.f ? v : 0.f;
      const long row = r0 + kgrp * 4 + r;
      const int  col = dt * 16 + arow;
      if (WRITE_BF16) ((short*)out_)[row * DD + col] = f2bf(v);
      else            ((float*)out_)[row * DD + col] = v;
    }
  }
}

// ---------------------------------------------------------------------------
extern "C" void kernel_launch(void* const* d_in, const int* in_sizes, int n_in,
                              void* d_out, int out_size, void* d_ws, size_t ws_size,
                              hipStream_t stream)
{
  const float* A  = (const float*)d_in[0];   // [16384][16384]
  const float* X  = (const float*)d_in[1];   // [16384][128]
  const float* W0 = (const float*)d_in[2];   // [128][128]
  const float* W1 = (const float*)d_in[3];   // [128][128]

  short* Tf = (short*)d_ws;                  // bf16 fragment-major T (4 MB)
  short* H1 = Tf + (size_t)DD * NN;          // bf16 [16384][128] post-relu H1

  // layer 0: T0 = X @ W0 ; H1 = relu(A @ T0)
  small_gemm<0><<<NN / 16, 256, 0, stream>>>(X, W0, Tf);
  agg_kernel<1><<<NN / 16, 64, 0, stream>>>(A, Tf, H1);
  // layer 1: T1 = H1 @ W1 ; out = relu(A @ T1)
  small_gemm<1><<<NN / 16, 256, 0, stream>>>(H1, W1, Tf);
  agg_kernel<0><<<NN / 16, 64, 0, stream>>>(A, Tf, d_out);
}

// Round 5
// 594.648 us; speedup vs baseline: 1.3232x; 1.3232x over previous
//
#include <hip/hip_runtime.h>
#include <hip/hip_bf16.h>

#define NN 16384
#define DD 128
#define BK 64          // k per pipeline stage
#define NT (NN / BK)   // 256 stages

typedef __attribute__((ext_vector_type(8))) short short8;
typedef __attribute__((ext_vector_type(4))) float f32x4;

__device__ __forceinline__ short f2bf(float f) {
  union { float f; unsigned u; } v; v.f = f;
  unsigned r = v.u + 0x7fffu + ((v.u >> 16) & 1u);   // RNE f32->bf16
  return (short)(r >> 16);
}
__device__ __forceinline__ float bf2f(short s) {
  union { unsigned u; float f; } v; v.u = ((unsigned)(unsigned short)s) << 16;
  return v.f;
}

#define WAITV(n) asm volatile("s_waitcnt vmcnt(" #n ")" ::: "memory")
#define BAR()    do { __builtin_amdgcn_s_barrier(); asm volatile("" ::: "memory"); } while (0)

// ---------------------------------------------------------------------------
// small GEMM: T = In @ W, written in MFMA B-fragment-major layout:
//   element (d, k):  kt=k>>5, dt=d>>4, lane=(d&15)|(((k>>3)&3)<<4), e=k&7
//   Tf[(((kt*8)+dt)*64 + lane)*8 + e]
// ---------------------------------------------------------------------------
template<int IN_BF16>
__global__ __launch_bounds__(256, 1)
void small_gemm(const void* __restrict__ In_, const float* __restrict__ W,
                short* __restrict__ Tf)
{
  __shared__ float sW[DD * DD];   // 64 KB
  const int tid = threadIdx.x;
  {
    const float4* W4 = (const float4*)W;
    float4* sW4 = (float4*)sW;
#pragma unroll
    for (int i = 0; i < 16; ++i) sW4[tid + 256 * i] = W4[tid + 256 * i];
  }
  __syncthreads();

  const int k0 = blockIdx.x * 16;
  const int kk = tid & 15;        // k-row within tile
  const int q  = tid >> 4;        // d-chunk 0..15 -> d = 8q..8q+7
  const long rowoff = (long)(k0 + kk) * DD;

  float acc[8] = {0.f, 0.f, 0.f, 0.f, 0.f, 0.f, 0.f, 0.f};
  if (IN_BF16) {
    const short8* In8 = (const short8*)((const short*)In_ + rowoff);
    for (int j8 = 0; j8 < 16; ++j8) {
      short8 a8 = In8[j8];
#pragma unroll
      for (int c = 0; c < 8; ++c) {
        float a = bf2f(a8[c]);
#pragma unroll
        for (int dd = 0; dd < 8; ++dd)
          acc[dd] += a * sW[(j8 * 8 + c) * DD + q * 8 + dd];
      }
    }
  } else {
    const float4* In4 = (const float4*)((const float*)In_ + rowoff);
    for (int j4 = 0; j4 < 32; ++j4) {
      float4 a4 = In4[j4];
      float av[4] = {a4.x, a4.y, a4.z, a4.w};
#pragma unroll
      for (int c = 0; c < 4; ++c)
#pragma unroll
        for (int dd = 0; dd < 8; ++dd)
          acc[dd] += av[c] * sW[(j4 * 4 + c) * DD + q * 8 + dd];
    }
  }

  const int k    = k0 + kk;
  const int kt   = k >> 5;
  const int ksub = (k >> 3) & 3;
  const int e    = k & 7;
#pragma unroll
  for (int dd = 0; dd < 8; ++dd) {
    const int d  = q * 8 + dd;
    const int dt = d >> 4;
    const int lf = (d & 15) | (ksub << 4);
    Tf[((((long)kt * 8) + dt) * 64 + lf) * 8 + e] = f2bf(acc[dd]);
  }
}

// ---------------------------------------------------------------------------
// aggregation: Out = relu(A @ T), T fragment-major bf16.
// Block = 64 rows (4 waves x 16 rows), grid 256 = 1 block/CU.
// B: staged block-wide via global_load_lds (linear, matches frag layout),
//    4-buffer LDS pipeline, prefetch distance 3, counted vmcnt (never 0),
//    raw s_barrier; stage issued AFTER barrier (WAR-safe at distance 3).
// A: direct global->reg (nontemporal, keeps Tf L2-resident), fp32->bf16 in reg.
// ---------------------------------------------------------------------------
template<int WRITE_BF16>
__global__ __launch_bounds__(256, 1)
void agg_kernel(const float* __restrict__ A, const short* __restrict__ Bf,
                void* __restrict__ out_)
{
  __shared__ __align__(16) short sB[4 * 8192];   // 4 bufs x 16 KB

  const int tid  = threadIdx.x;
  const int lane = tid & 63;
  const int w    = tid >> 6;                     // wave 0..3
  const long r0  = (long)blockIdx.x * 64 + w * 16;
  const int arow = lane & 15;
  const int kgrp = lane >> 4;

  const float* aptr = A + (r0 + arow) * (long)NN + kgrp * 8;
  const short* gsrc = Bf + w * 2048 + lane * 8;  // wave's quarter of a 16KB tile
  short* lbase = &sB[0] + w * 2048;              // wave-uniform LDS dest base

  f32x4 acc[8];
#pragma unroll
  for (int dt = 0; dt < 8; ++dt) acc[dt] = (f32x4){0.f, 0.f, 0.f, 0.f};

  auto STAGE = [&](int buf, int t) {
    const short* g = gsrc + (long)t * 8192;
    short* l = lbase + buf * 8192;
#pragma unroll
    for (int i = 0; i < 4; ++i)
      __builtin_amdgcn_global_load_lds(
          (const __attribute__((address_space(1))) unsigned int*)(g + i * 512),
          (__attribute__((address_space(3))) unsigned int*)(l + i * 512),
          16, 0, 0);
  };
  auto ALOAD = [&](f32x4 (&ar)[4], int t) {
    const float* p = aptr + (long)t * BK;
    ar[0] = __builtin_nontemporal_load((const f32x4*)p);
    ar[1] = __builtin_nontemporal_load((const f32x4*)(p + 4));
    ar[2] = __builtin_nontemporal_load((const f32x4*)(p + 32));
    ar[3] = __builtin_nontemporal_load((const f32x4*)(p + 36));
  };
  auto COMPUTE = [&](int buf, f32x4 (&ar)[4]) {
    const short* lb = &sB[0] + buf * 8192 + lane * 8;
#pragma unroll
    for (int ks = 0; ks < 2; ++ks) {
      short8 af;
      af[0] = f2bf(ar[2 * ks].x); af[1] = f2bf(ar[2 * ks].y);
      af[2] = f2bf(ar[2 * ks].z); af[3] = f2bf(ar[2 * ks].w);
      af[4] = f2bf(ar[2 * ks + 1].x); af[5] = f2bf(ar[2 * ks + 1].y);
      af[6] = f2bf(ar[2 * ks + 1].z); af[7] = f2bf(ar[2 * ks + 1].w);
#pragma unroll
      for (int dt = 0; dt < 8; ++dt) {
        short8 bf = *(const short8*)(lb + ks * 4096 + dt * 512);
        acc[dt] = __builtin_amdgcn_mfma_f32_16x16x32_bf16(af, bf, acc[dt], 0, 0, 0);
      }
    }
  };

  f32x4 a0[4], a1[4], a2[4], a3[4];

  // prologue: stage tiles 0,1,2 (24 VMEM outstanding)
  STAGE(0, 0); ALOAD(a0, 0);
  STAGE(1, 1); ALOAD(a1, 1);
  STAGE(2, 2); ALOAD(a2, 2);

  int t = 0;
  for (; t < NT - 4; t += 4) {
    WAITV(16); BAR(); STAGE(3, t + 3); ALOAD(a3, t + 3); COMPUTE(0, a0);
    WAITV(16); BAR(); STAGE(0, t + 4); ALOAD(a0, t + 4); COMPUTE(1, a1);
    WAITV(16); BAR(); STAGE(1, t + 5); ALOAD(a1, t + 5); COMPUTE(2, a2);
    WAITV(16); BAR(); STAGE(2, t + 6); ALOAD(a2, t + 6); COMPUTE(3, a3);
  }
  // t == NT-4: last stage is tile NT-1, then drain
  WAITV(16); BAR(); STAGE(3, t + 3); ALOAD(a3, t + 3); COMPUTE(0, a0);
  WAITV(16); BAR(); COMPUTE(1, a1);
  WAITV(8);  BAR(); COMPUTE(2, a2);
  WAITV(0);  BAR(); COMPUTE(3, a3);

  // epilogue: relu + store (C layout: row = kgrp*4 + r, col = dt*16 + arow)
#pragma unroll
  for (int dt = 0; dt < 8; ++dt) {
#pragma unroll
    for (int r = 0; r < 4; ++r) {
      float v = acc[dt][r];
      v = v > 0.f ? v : 0.f;
      const long row = r0 + kgrp * 4 + r;
      const int  col = dt * 16 + arow;
      if (WRITE_BF16)
        __builtin_nontemporal_store(f2bf(v), (short*)out_ + row * DD + col);
      else
        __builtin_nontemporal_store(v, (float*)out_ + row * DD + col);
    }
  }
}

// ---------------------------------------------------------------------------
extern "C" void kernel_launch(void* const* d_in, const int* in_sizes, int n_in,
                              void* d_out, int out_size, void* d_ws, size_t ws_size,
                              hipStream_t stream)
{
  const float* A  = (const float*)d_in[0];   // [16384][16384]
  const float* X  = (const float*)d_in[1];   // [16384][128]
  const float* W0 = (const float*)d_in[2];   // [128][128]
  const float* W1 = (const float*)d_in[3];   // [128][128]

  short* Tf = (short*)d_ws;                  // bf16 fragment-major T (4 MB)
  short* H1 = Tf + (size_t)DD * NN;          // bf16 [16384][128] post-relu H1

  // layer 0: T0 = X @ W0 ; H1 = relu(A @ T0)
  small_gemm<0><<<NN / 16, 256, 0, stream>>>(X, W0, Tf);
  agg_kernel<1><<<NN / 64, 256, 0, stream>>>(A, Tf, H1);
  // layer 1: T1 = H1 @ W1 ; out = relu(A @ T1)
  small_gemm<1><<<NN / 16, 256, 0, stream>>>(H1, W1, Tf);
  agg_kernel<0><<<NN / 64, 256, 0, stream>>>(A, Tf, d_out);
}